// Round 7
// baseline (73.300 us; speedup 1.0000x reference)
//
#include <hip/hip_runtime.h>
#include <hip/hip_bf16.h>
#include <math.h>

#define B_    4
#define N_    2048
#define INF_  256
#define OUTF_ 64
#define H_    8
#define C_    512   // H_*OUTF_

typedef __attribute__((ext_vector_type(8))) short  bf16x8;
typedef __attribute__((ext_vector_type(4))) short  s16x4;
typedef __attribute__((ext_vector_type(4))) float  f32x4;

static __device__ __forceinline__ short f2b(float f) {
    union { float f; unsigned u; } v; v.f = f;
    unsigned r = (v.u + 0x7FFFu + ((v.u >> 16) & 1u)) >> 16;  // RNE
    return (short)r;
}
static __device__ __forceinline__ float b2f(short s) {
    union { unsigned u; float f; } v; v.u = ((unsigned)(unsigned short)s) << 16;
    return v.f;
}
static __device__ __forceinline__ bf16x8 bits2bf16(unsigned byte) {
    bf16x8 f;
#pragma unroll
    for (int u = 0; u < 8; ++u) f[u] = ((byte >> u) & 1u) ? (short)0x3F80 : (short)0;
    return f;
}

#define GL2LDS(gsrc, ldst)                                                          \
    __builtin_amdgcn_global_load_lds(                                               \
        (const __attribute__((address_space(1))) void*)(gsrc),                      \
        (__attribute__((address_space(3))) void*)(ldst), 16, 0, 0)

// ---------------------------------------------------------------------------
// Kernel 1: fused pack + casts (one launch).
//   blocks [0,2048):       adj -> bitmask bm (1 bit per edge; wave ballot)
//   blocks [2048,3072):    x -> xb (bf16)
//   blocks [3072,3104):    W[256][512] -> wbT[512][256] (bf16 transposed)
// ---------------------------------------------------------------------------
__global__ __launch_bounds__(256)
void cast_kernel(const float* __restrict__ x, const float* __restrict__ w,
                 const int* __restrict__ adj,
                 short* __restrict__ xb, short* __restrict__ wbT,
                 unsigned char* __restrict__ bm) {
    __shared__ short T[64][72];
    const int bid = blockIdx.x;
    if (bid < 2048) {
        // one wave per adjacency row; bit j of word it = (adj[row, it*64+j] != 0)
        const int wid  = threadIdx.x >> 6;
        const int lane = threadIdx.x & 63;
        const int row  = bid * 4 + wid;           // 0..8191 (= b*N + i)
        const int* arow = adj + (size_t)row * N_;
        unsigned long long myword = 0;
#pragma unroll
        for (int it = 0; it < 32; ++it) {
            int v = arow[it * 64 + lane];
            unsigned long long m = __ballot(v != 0);
            if (lane == it) myword = m;
        }
        if (lane < 32)
            *reinterpret_cast<unsigned long long*>(bm + (size_t)row * 256 + lane * 8) = myword;
    } else if (bid < 3072) {
        size_t i8 = (size_t)(bid - 2048) * 256 + threadIdx.x;
        const float4* p = reinterpret_cast<const float4*>(x + i8 * 8);
        float4 v0 = p[0], v1 = p[1];
        bf16x8 o;
        o[0] = f2b(v0.x); o[1] = f2b(v0.y); o[2] = f2b(v0.z); o[3] = f2b(v0.w);
        o[4] = f2b(v1.x); o[5] = f2b(v1.y); o[6] = f2b(v1.z); o[7] = f2b(v1.w);
        *reinterpret_cast<bf16x8*>(xb + i8 * 8) = o;
    } else {
        int blk = bid - 3072;                 // 32 blocks: 8 c-tiles x 4 k-tiles
        int c0 = (blk & 7) * 64;
        int k0 = (blk >> 3) * 64;
        int t = threadIdx.x;
        int cl = (t & 15) * 4;
#pragma unroll
        for (int p = 0; p < 4; ++p) {
            int kl = p * 16 + (t >> 4);
            float4 v = *reinterpret_cast<const float4*>(&w[(size_t)(k0 + kl) * C_ + c0 + cl]);
            T[cl + 0][kl] = f2b(v.x);
            T[cl + 1][kl] = f2b(v.y);
            T[cl + 2][kl] = f2b(v.z);
            T[cl + 3][kl] = f2b(v.w);
        }
        __syncthreads();
        int cr = t >> 2;
        int ks = (t & 3) * 16;
        short* dst = &wbT[(size_t)(c0 + cr) * INF_ + k0 + ks];
        *reinterpret_cast<bf16x8*>(dst)     = *reinterpret_cast<const bf16x8*>(&T[cr][ks]);
        *reinterpret_cast<bf16x8*>(dst + 8) = *reinterpret_cast<const bf16x8*>(&T[cr][ks + 8]);
    }
}

// ---------------------------------------------------------------------------
// Kernel 2: fused projection (bf16 MFMA) + e + gT.  (unchanged, validated)
// ---------------------------------------------------------------------------
__global__ __launch_bounds__(256)
void proj_fused(const short* __restrict__ xb, const short* __restrict__ wbT,
                const float* __restrict__ attn_dst,
                short* __restrict__ ebT, short* __restrict__ gT) {
    __shared__ char smem[24576];
    short* As = (short*)smem;                  // 16 KiB  [128][64] swizzled
    short* Bs = (short*)(smem + 16384);        //  8 KiB  [64][64]  swizzled
    short* Tt = (short*)smem;                  // 64 x 136 bf16 = 17408 B
    float* Sr = (float*)(smem + 17408);        // 2 x 128 f32   = 1024 B
    short* Eb = (short*)(smem + 18432);        // 128 bf16      = 256 B

    const int m0 = blockIdx.x * 128;
    const int n0 = blockIdx.y * 64;
    const int head = n0 >> 6;
    const int b    = m0 >> 11;
    const int j0g  = m0 & (N_ - 1);
    const int wid  = threadIdx.x >> 6;
    const int lane = threadIdx.x & 63;
    const int wr = wid >> 1, wc = wid & 1;
    const int q4 = lane >> 4, l15 = lane & 15;
    const int lr = lane >> 3;
    const int ls = (lane & 7) ^ lr;
    const short* Abase = xb + (size_t)m0 * INF_;
    const short* Bbase = wbT + (size_t)n0 * INF_;

    f32x4 acc[4][2];
#pragma unroll
    for (int m = 0; m < 4; ++m)
#pragma unroll
        for (int n = 0; n < 2; ++n) acc[m][n] = (f32x4){0.f, 0.f, 0.f, 0.f};

    for (int k0 = 0; k0 < INF_; k0 += 64) {
#pragma unroll
        for (int q = 0; q < 4; ++q) {
            int chunk = wid * 4 + q;
            int row   = chunk * 8 + lr;
            GL2LDS(Abase + (size_t)row * INF_ + k0 + ls * 8, As + chunk * 512);
        }
#pragma unroll
        for (int q = 0; q < 2; ++q) {
            int chunk = wid * 2 + q;
            int row   = chunk * 8 + lr;
            GL2LDS(Bbase + (size_t)row * INF_ + k0 + ls * 8, Bs + chunk * 512);
        }
        __syncthreads();
#pragma unroll
        for (int kk = 0; kk < 2; ++kk) {
            const int ko = kk * 32 + q4 * 8;
            bf16x8 a[4], bb[2];
#pragma unroll
            for (int m = 0; m < 4; ++m) {
                int row = wr * 64 + m * 16 + l15;
                a[m] = *reinterpret_cast<const bf16x8*>(&As[row * 64 + (ko ^ ((row & 7) * 8))]);
            }
#pragma unroll
            for (int n = 0; n < 2; ++n) {
                int row = wc * 32 + n * 16 + l15;
                bb[n] = *reinterpret_cast<const bf16x8*>(&Bs[row * 64 + (ko ^ ((row & 7) * 8))]);
            }
#pragma unroll
            for (int m = 0; m < 4; ++m)
#pragma unroll
                for (int n = 0; n < 2; ++n)
                    acc[m][n] = __builtin_amdgcn_mfma_f32_16x16x32_bf16(a[m], bb[n], acc[m][n], 0, 0, 0);
        }
        __syncthreads();
    }

    float af0 = attn_dst[head * 64 + wc * 32 + l15];
    float af1 = attn_dst[head * 64 + wc * 32 + 16 + l15];
#pragma unroll
    for (int m = 0; m < 4; ++m) {
        f32x4 part;
#pragma unroll
        for (int r = 0; r < 4; ++r)
            part[r] = acc[m][0][r] * af0 + acc[m][1][r] * af1;
#pragma unroll
        for (int off = 1; off < 16; off <<= 1)
#pragma unroll
            for (int r = 0; r < 4; ++r) part[r] += __shfl_xor(part[r], off);
        if (l15 == 0)
            *reinterpret_cast<f32x4*>(&Sr[wc * 128 + wr * 64 + m * 16 + q4 * 4]) = part;
    }
    __syncthreads();
    const int t = threadIdx.x;
    if (t < 128) {
        float s = Sr[t] + Sr[128 + t];
        short eb = f2b(expf(s));
        Eb[t] = eb;
        ebT[((size_t)b * H_ + head) * N_ + j0g + t] = eb;
    }
    __syncthreads();
#pragma unroll
    for (int m = 0; m < 4; ++m) {
        int jl = wr * 64 + m * 16 + q4 * 4;
        float ev[4];
#pragma unroll
        for (int r = 0; r < 4; ++r) ev[r] = b2f(Eb[jl + r]);
#pragma unroll
        for (int n = 0; n < 2; ++n) {
            int cl = wc * 32 + n * 16 + l15;
            s16x4 gv;
#pragma unroll
            for (int r = 0; r < 4; ++r) gv[r] = f2b(acc[m][n][r] * ev[r]);
            *reinterpret_cast<s16x4*>(&Tt[cl * 136 + jl]) = gv;
        }
    }
    __syncthreads();
    {
        int c  = t >> 2;
        int jc = (t & 3) * 32;
        short* dst = &gT[((size_t)b * C_ + n0 + c) * N_ + j0g + jc];
#pragma unroll
        for (int u = 0; u < 4; ++u)
            *reinterpret_cast<bf16x8*>(dst + u * 8) =
                *reinterpret_cast<const bf16x8*>(&Tt[c * 136 + jc + u * 8]);
    }
}

// ---------------------------------------------------------------------------
// Kernel 3: numerator GEMM (bf16 MFMA) + denominator + divide.
// A-operand from BITMASK (per-lane u64 loads + 8-bit->bf16x8 expansion in
// VGPRs; no A-LDS, no A staging stall). B (gT) double-buffered GL2LDS with
// XOR swizzle; one barrier per K-step.  8 waves (4m x 2n), wave tile 32x32,
// BM=128, BN=64 (one head).  XCD-chunked block swizzle for L2 locality.
//   num[i,c] = sum_j adj * gT[b,c,j] ;  den[i] = sum_j adj * e[b,head,j]
//   out = num / den
// ---------------------------------------------------------------------------
__global__ __launch_bounds__(512)
void agg_mfma(const unsigned char* __restrict__ bm, const short* __restrict__ gT,
              const short* __restrict__ ebT, float* __restrict__ out) {
    __shared__ short Bs[2][64 * 64];    // 16 KiB double-buffered
    __shared__ short Es[N_];            //  4 KiB
    __shared__ float Dr[128];

    // XCD-chunked swizzle: 512 blocks -> 8 chunks of 64; consecutive work
    // (same head/batch B-panel) lands on one XCD's L2.
    const int work = (blockIdx.x & 7) * 64 + (blockIdx.x >> 3);
    const int mt = work & 15;
    const int nh = (work >> 4) & 7;
    const int b  = work >> 7;
    const int m0 = mt * 128;
    const int n0 = nh * 64;

    const int tid  = threadIdx.x;
    const int wid  = tid >> 6;              // 0..7
    const int lane = tid & 63;
    const int wr = wid >> 1, wc = wid & 1;  // 4 x 2 waves
    const int q4 = lane >> 4, l15 = lane & 15;
    const int lr = lane >> 3;
    const int ls = (lane & 7) ^ lr;

    const unsigned char* Mrow0 = bm + ((size_t)b * N_ + m0 + wr * 32 + l15) * 256;
    const unsigned char* Mrow1 = Mrow0 + 16 * 256;
    const short* Bbase = gT  + ((size_t)b * C_ + n0) * N_;
    const short* Ebase = ebT + ((size_t)b * H_ + nh) * N_;

#define STAGE_B(buf, k0s) do {                                                  \
        int row_ = wid * 8 + lr;                                                \
        GL2LDS(Bbase + (size_t)row_ * N_ + (k0s) + ls * 8, &Bs[buf][wid * 512]);\
    } while (0)

    f32x4 acc[2][2];
    f32x4 accd = (f32x4){0.f, 0.f, 0.f, 0.f};
#pragma unroll
    for (int m = 0; m < 2; ++m)
#pragma unroll
        for (int n = 0; n < 2; ++n) acc[m][n] = (f32x4){0.f, 0.f, 0.f, 0.f};

    // prologue: E + B tile 0 + A bits tile 0
    if (wid < 4) GL2LDS(Ebase + wid * 512 + lane * 8, Es + wid * 512);
    STAGE_B(0, 0);
    unsigned long long u0 = *reinterpret_cast<const unsigned long long*>(Mrow0);
    unsigned long long u1 = *reinterpret_cast<const unsigned long long*>(Mrow1);
    __syncthreads();

    for (int t = 0; t < 32; ++t) {
        const int buf = t & 1;
        const int k0  = t * 64;
        unsigned long long nu0 = 0, nu1 = 0;
        if (t < 31) {                    // prefetch next tile (issue-early)
            STAGE_B(buf ^ 1, k0 + 64);
            nu0 = *reinterpret_cast<const unsigned long long*>(Mrow0 + (k0 >> 3) + 8);
            nu1 = *reinterpret_cast<const unsigned long long*>(Mrow1 + (k0 >> 3) + 8);
        }
        // compute current tile (A expanded from bits in-register)
#pragma unroll
        for (int kk = 0; kk < 2; ++kk) {
            const int gA = kk * 4 + q4;          // k-octet index 0..7
            bf16x8 a[2], bb[2], be;
            a[0] = bits2bf16((unsigned)(u0 >> (gA * 8)) & 0xFFu);
            a[1] = bits2bf16((unsigned)(u1 >> (gA * 8)) & 0xFFu);
#pragma unroll
            for (int n = 0; n < 2; ++n) {
                int row = wc * 32 + n * 16 + l15;
                bb[n] = *reinterpret_cast<const bf16x8*>(&Bs[buf][row * 64 + (gA ^ (row & 7)) * 8]);
            }
            be = *reinterpret_cast<const bf16x8*>(&Es[k0 + gA * 8]);
#pragma unroll
            for (int m = 0; m < 2; ++m)
#pragma unroll
                for (int n = 0; n < 2; ++n)
                    acc[m][n] = __builtin_amdgcn_mfma_f32_16x16x32_bf16(a[m], bb[n], acc[m][n], 0, 0, 0);
            // balanced den: wave (wr,wc) covers rows wr*32 + wc*16 + 0..15
            accd = __builtin_amdgcn_mfma_f32_16x16x32_bf16(wc ? a[1] : a[0], be, accd, 0, 0, 0);
        }
        u0 = nu0; u1 = nu1;
        __syncthreads();
    }

    // den -> LDS
    if (l15 == 0)
        *reinterpret_cast<f32x4*>(&Dr[wr * 32 + wc * 16 + q4 * 4]) = accd;
    __syncthreads();

    float* obase = out + (size_t)b * N_ * C_;
#pragma unroll
    for (int m = 0; m < 2; ++m) {
        int jl = wr * 32 + m * 16 + q4 * 4;
        float inv[4];
#pragma unroll
        for (int r = 0; r < 4; ++r) inv[r] = 1.0f / Dr[jl + r];
#pragma unroll
        for (int n = 0; n < 2; ++n) {
            int gc = n0 + wc * 32 + n * 16 + l15;
#pragma unroll
            for (int r = 0; r < 4; ++r)
                obase[(size_t)(m0 + jl + r) * C_ + gc] = acc[m][n][r] * inv[r];
        }
    }
#undef STAGE_B
}

// ---------------------------------------------------------------------------
extern "C" void kernel_launch(void* const* d_in, const int* in_sizes, int n_in,
                              void* d_out, int out_size, void* d_ws, size_t ws_size,
                              hipStream_t stream) {
    const float* x        = (const float*)d_in[0];
    const int*   adj      = (const int*)d_in[1];
    const float* weight   = (const float*)d_in[2];
    // d_in[3] = attn_src : unused (cancels in softmax over neighbors j)
    const float* attn_dst = (const float*)d_in[4];
    float* out = (float*)d_out;

    // workspace:
    //   xb  : 4 MiB bf16
    //   wbT : 256 KiB bf16
    //   ebT : 128 KiB bf16   [b][h][j]
    //   gT  : 8 MiB bf16     [b][c][j]
    //   bm  : 2 MiB bitmask  [b*N + i][N/8 bytes]
    short* xb  = (short*)d_ws;
    short* wbT = xb + (size_t)B_ * N_ * INF_;
    short* ebT = wbT + (size_t)C_ * INF_;
    short* gT  = ebT + (size_t)B_ * H_ * N_;
    unsigned char* bmp = (unsigned char*)(gT + (size_t)B_ * C_ * N_);

    // 1. fused pack (adj->bits) + casts (x->xb, W->wbT)
    cast_kernel<<<dim3(2048 + 1024 + 32), 256, 0, stream>>>(x, weight, adj, xb, wbT, bmp);
    // 2. fused projection + e + gT
    proj_fused<<<dim3((B_ * N_) / 128, C_ / 64), 256, 0, stream>>>(xb, wbT, attn_dst, ebT, gT);
    // 3. numerator GEMM + denominator (MFMA) + divide -> out (bitmask A)
    agg_mfma<<<dim3(512), 512, 0, stream>>>(bmp, gT, ebT, out);
}

// Round 8
// 67.058 us; speedup vs baseline: 1.0931x; 1.0931x over previous
//
#include <hip/hip_runtime.h>
#include <hip/hip_bf16.h>
#include <math.h>

#define B_    4
#define N_    2048
#define INF_  256
#define OUTF_ 64
#define H_    8
#define C_    512   // H_*OUTF_

typedef __attribute__((ext_vector_type(8))) short  bf16x8;
typedef __attribute__((ext_vector_type(4))) short  s16x4;
typedef __attribute__((ext_vector_type(4))) float  f32x4;

static __device__ __forceinline__ short f2b(float f) {
    union { float f; unsigned u; } v; v.f = f;
    unsigned r = (v.u + 0x7FFFu + ((v.u >> 16) & 1u)) >> 16;  // RNE
    return (short)r;
}
static __device__ __forceinline__ float b2f(short s) {
    union { unsigned u; float f; } v; v.u = ((unsigned)(unsigned short)s) << 16;
    return v.f;
}
static __device__ __forceinline__ bf16x8 bits2bf16(unsigned byte) {
    bf16x8 f;
#pragma unroll
    for (int u = 0; u < 8; ++u) f[u] = ((byte >> u) & 1u) ? (short)0x3F80 : (short)0;
    return f;
}

#define GL2LDS(gsrc, ldst)                                                          \
    __builtin_amdgcn_global_load_lds(                                               \
        (const __attribute__((address_space(1))) void*)(gsrc),                      \
        (__attribute__((address_space(3))) void*)(ldst), 16, 0, 0)

#define WAITV2() asm volatile("s_waitcnt vmcnt(2)" ::: "memory")
#define WAITV0() asm volatile("s_waitcnt vmcnt(0)" ::: "memory")
#define BAR()    do { asm volatile("" ::: "memory"); __builtin_amdgcn_s_barrier(); \
                      asm volatile("" ::: "memory"); } while (0)

// ---------------------------------------------------------------------------
// Kernel 1: fused pack + casts (one launch).
//   blocks [0,2048):       adj -> bitmask bm (1 bit per edge; wave ballot)
//   blocks [2048,3072):    x -> xb (bf16)
//   blocks [3072,3104):    W[256][512] -> wbT[512][256] (bf16 transposed)
// ---------------------------------------------------------------------------
__global__ __launch_bounds__(256)
void cast_kernel(const float* __restrict__ x, const float* __restrict__ w,
                 const int* __restrict__ adj,
                 short* __restrict__ xb, short* __restrict__ wbT,
                 unsigned char* __restrict__ bm) {
    __shared__ short T[64][72];
    const int bid = blockIdx.x;
    if (bid < 2048) {
        const int wid  = threadIdx.x >> 6;
        const int lane = threadIdx.x & 63;
        const int row  = bid * 4 + wid;           // 0..8191 (= b*N + i)
        const int* arow = adj + (size_t)row * N_;
        unsigned long long myword = 0;
#pragma unroll
        for (int it = 0; it < 32; ++it) {
            int v = arow[it * 64 + lane];
            unsigned long long m = __ballot(v != 0);
            if (lane == it) myword = m;
        }
        if (lane < 32)
            *reinterpret_cast<unsigned long long*>(bm + (size_t)row * 256 + lane * 8) = myword;
    } else if (bid < 3072) {
        size_t i8 = (size_t)(bid - 2048) * 256 + threadIdx.x;
        const float4* p = reinterpret_cast<const float4*>(x + i8 * 8);
        float4 v0 = p[0], v1 = p[1];
        bf16x8 o;
        o[0] = f2b(v0.x); o[1] = f2b(v0.y); o[2] = f2b(v0.z); o[3] = f2b(v0.w);
        o[4] = f2b(v1.x); o[5] = f2b(v1.y); o[6] = f2b(v1.z); o[7] = f2b(v1.w);
        *reinterpret_cast<bf16x8*>(xb + i8 * 8) = o;
    } else {
        int blk = bid - 3072;                 // 32 blocks: 8 c-tiles x 4 k-tiles
        int c0 = (blk & 7) * 64;
        int k0 = (blk >> 3) * 64;
        int t = threadIdx.x;
        int cl = (t & 15) * 4;
#pragma unroll
        for (int p = 0; p < 4; ++p) {
            int kl = p * 16 + (t >> 4);
            float4 v = *reinterpret_cast<const float4*>(&w[(size_t)(k0 + kl) * C_ + c0 + cl]);
            T[cl + 0][kl] = f2b(v.x);
            T[cl + 1][kl] = f2b(v.y);
            T[cl + 2][kl] = f2b(v.z);
            T[cl + 3][kl] = f2b(v.w);
        }
        __syncthreads();
        int cr = t >> 2;
        int ks = (t & 3) * 16;
        short* dst = &wbT[(size_t)(c0 + cr) * INF_ + k0 + ks];
        *reinterpret_cast<bf16x8*>(dst)     = *reinterpret_cast<const bf16x8*>(&T[cr][ks]);
        *reinterpret_cast<bf16x8*>(dst + 8) = *reinterpret_cast<const bf16x8*>(&T[cr][ks + 8]);
    }
}

// ---------------------------------------------------------------------------
// Kernel 2: fused projection (bf16 MFMA) + e + gT.  (unchanged, validated)
// ---------------------------------------------------------------------------
__global__ __launch_bounds__(256)
void proj_fused(const short* __restrict__ xb, const short* __restrict__ wbT,
                const float* __restrict__ attn_dst,
                short* __restrict__ ebT, short* __restrict__ gT) {
    __shared__ char smem[24576];
    short* As = (short*)smem;                  // 16 KiB  [128][64] swizzled
    short* Bs = (short*)(smem + 16384);        //  8 KiB  [64][64]  swizzled
    short* Tt = (short*)smem;                  // 64 x 136 bf16 = 17408 B
    float* Sr = (float*)(smem + 17408);        // 2 x 128 f32   = 1024 B
    short* Eb = (short*)(smem + 18432);        // 128 bf16      = 256 B

    const int m0 = blockIdx.x * 128;
    const int n0 = blockIdx.y * 64;
    const int head = n0 >> 6;
    const int b    = m0 >> 11;
    const int j0g  = m0 & (N_ - 1);
    const int wid  = threadIdx.x >> 6;
    const int lane = threadIdx.x & 63;
    const int wr = wid >> 1, wc = wid & 1;
    const int q4 = lane >> 4, l15 = lane & 15;
    const int lr = lane >> 3;
    const int ls = (lane & 7) ^ lr;
    const short* Abase = xb + (size_t)m0 * INF_;
    const short* Bbase = wbT + (size_t)n0 * INF_;

    f32x4 acc[4][2];
#pragma unroll
    for (int m = 0; m < 4; ++m)
#pragma unroll
        for (int n = 0; n < 2; ++n) acc[m][n] = (f32x4){0.f, 0.f, 0.f, 0.f};

    for (int k0 = 0; k0 < INF_; k0 += 64) {
#pragma unroll
        for (int q = 0; q < 4; ++q) {
            int chunk = wid * 4 + q;
            int row   = chunk * 8 + lr;
            GL2LDS(Abase + (size_t)row * INF_ + k0 + ls * 8, As + chunk * 512);
        }
#pragma unroll
        for (int q = 0; q < 2; ++q) {
            int chunk = wid * 2 + q;
            int row   = chunk * 8 + lr;
            GL2LDS(Bbase + (size_t)row * INF_ + k0 + ls * 8, Bs + chunk * 512);
        }
        __syncthreads();
#pragma unroll
        for (int kk = 0; kk < 2; ++kk) {
            const int ko = kk * 32 + q4 * 8;
            bf16x8 a[4], bb[2];
#pragma unroll
            for (int m = 0; m < 4; ++m) {
                int row = wr * 64 + m * 16 + l15;
                a[m] = *reinterpret_cast<const bf16x8*>(&As[row * 64 + (ko ^ ((row & 7) * 8))]);
            }
#pragma unroll
            for (int n = 0; n < 2; ++n) {
                int row = wc * 32 + n * 16 + l15;
                bb[n] = *reinterpret_cast<const bf16x8*>(&Bs[row * 64 + (ko ^ ((row & 7) * 8))]);
            }
#pragma unroll
            for (int m = 0; m < 4; ++m)
#pragma unroll
                for (int n = 0; n < 2; ++n)
                    acc[m][n] = __builtin_amdgcn_mfma_f32_16x16x32_bf16(a[m], bb[n], acc[m][n], 0, 0, 0);
        }
        __syncthreads();
    }

    float af0 = attn_dst[head * 64 + wc * 32 + l15];
    float af1 = attn_dst[head * 64 + wc * 32 + 16 + l15];
#pragma unroll
    for (int m = 0; m < 4; ++m) {
        f32x4 part;
#pragma unroll
        for (int r = 0; r < 4; ++r)
            part[r] = acc[m][0][r] * af0 + acc[m][1][r] * af1;
#pragma unroll
        for (int off = 1; off < 16; off <<= 1)
#pragma unroll
            for (int r = 0; r < 4; ++r) part[r] += __shfl_xor(part[r], off);
        if (l15 == 0)
            *reinterpret_cast<f32x4*>(&Sr[wc * 128 + wr * 64 + m * 16 + q4 * 4]) = part;
    }
    __syncthreads();
    const int t = threadIdx.x;
    if (t < 128) {
        float s = Sr[t] + Sr[128 + t];
        short eb = f2b(expf(s));
        Eb[t] = eb;
        ebT[((size_t)b * H_ + head) * N_ + j0g + t] = eb;
    }
    __syncthreads();
#pragma unroll
    for (int m = 0; m < 4; ++m) {
        int jl = wr * 64 + m * 16 + q4 * 4;
        float ev[4];
#pragma unroll
        for (int r = 0; r < 4; ++r) ev[r] = b2f(Eb[jl + r]);
#pragma unroll
        for (int n = 0; n < 2; ++n) {
            int cl = wc * 32 + n * 16 + l15;
            s16x4 gv;
#pragma unroll
            for (int r = 0; r < 4; ++r) gv[r] = f2b(acc[m][n][r] * ev[r]);
            *reinterpret_cast<s16x4*>(&Tt[cl * 136 + jl]) = gv;
        }
    }
    __syncthreads();
    {
        int c  = t >> 2;
        int jc = (t & 3) * 32;
        short* dst = &gT[((size_t)b * C_ + n0 + c) * N_ + j0g + jc];
#pragma unroll
        for (int u = 0; u < 4; ++u)
            *reinterpret_cast<bf16x8*>(dst + u * 8) =
                *reinterpret_cast<const bf16x8*>(&Tt[c * 136 + jc + u * 8]);
    }
}

// ---------------------------------------------------------------------------
// Kernel 3: numerator GEMM (bf16 MFMA) + denominator + divide.
// BM=128, BN=128 (2 heads), 8 waves (4m x 2n), wave tile 32x64.
// adj-bits (32 KB, 16B-XOR-swizzled) + e rows (8 KB) staged to LDS once.
// B (gT) tiles: 3-buffer counted-vmcnt pipeline (depth 2, vmcnt(2) + raw
// s_barrier — each wave waits its OWN loads, then barrier => all visible;
// single barrier per iter is race-free because it follows compute).
// den per wave in-register: wave (wr,wc) owns rows x head(wc); the lane
// holding num[row,col] also holds den[row] -> no LDS exchange.
// ---------------------------------------------------------------------------
__global__ __launch_bounds__(512, 2)
void agg_mfma(const unsigned char* __restrict__ bm, const short* __restrict__ gT,
              const short* __restrict__ ebT, float* __restrict__ out) {
    __shared__ short Bs[3][8192];          // 3 x 16 KiB : [c 0..127][k 0..63] swizzled
    __shared__ unsigned char AB[32768];    // adj bits: 128 rows x 256 B, 16B-swizzled
    __shared__ short Es[2][2048];          // e rows of the block's 2 heads

    // XCD-chunked swizzle: 256 blocks -> 8 chunks of 32 (same gT n-panel/XCD)
    const int work = (blockIdx.x & 7) * 32 + (blockIdx.x >> 3);
    const int mt = work & 15;
    const int nt = (work >> 4) & 3;
    const int b  = work >> 6;
    const int m0 = mt * 128;
    const int n0 = nt * 128;
    const int h0 = n0 >> 6;

    const int tid  = threadIdx.x;
    const int wid  = tid >> 6;
    const int lane = tid & 63;
    const int wr = wid >> 1, wc = wid & 1;
    const int q4 = lane >> 4, l15 = lane & 15;
    const int lr = lane >> 3;
    const int ls = (lane & 7) ^ lr;

    const short* Bbase = gT + ((size_t)b * C_ + n0) * N_;

    // ---- prologue staging (order matters for vmcnt accounting) ----
    {   // adj bits: 4 x (1 KB per wave); lds[row][w16] <- gbl[row][w16 ^ (row&15)]
        const unsigned char* bmb = bm + ((size_t)b * N_ + m0) * 256;
#pragma unroll
        for (int p = 0; p < 4; ++p) {
            int row = p * 32 + wid * 4 + (lane >> 4);
            GL2LDS(bmb + (size_t)row * 256 + (((lane & 15) ^ (row & 15)) << 4),
                   AB + p * 8192 + wid * 1024);
        }
    }
    // e rows: head = wid>>2, quarter = wid&3
    GL2LDS(ebT + ((size_t)b * H_ + h0 + (wid >> 2)) * N_ + (wid & 3) * 512 + lane * 8,
           (short*)Es + wid * 512);

#define STAGE_B(buf, k0s) do {                                                       \
        GL2LDS(Bbase + (size_t)(wid * 16 + lr) * N_ + (k0s) + ls * 8,                \
               (buf) + wid * 1024);                                                  \
        GL2LDS(Bbase + (size_t)(wid * 16 + 8 + lr) * N_ + (k0s) + ls * 8,            \
               (buf) + wid * 1024 + 512);                                            \
    } while (0)

    f32x4 acc[2][4];
    f32x4 accd[2];
#pragma unroll
    for (int m = 0; m < 2; ++m) {
        accd[m] = (f32x4){0.f, 0.f, 0.f, 0.f};
#pragma unroll
        for (int n = 0; n < 4; ++n) acc[m][n] = (f32x4){0.f, 0.f, 0.f, 0.f};
    }

    short* bufA = &Bs[0][0];
    short* bufB = &Bs[1][0];
    short* bufC = &Bs[2][0];
    STAGE_B(bufA, 0);
    STAGE_B(bufB, 64);
    WAITV2();          // AB(4)+E(1)+B0(2) retired; B1(2) may be in flight
    BAR();

    const int r0  = wr * 32 + l15;
    const unsigned char* ab0 = AB + r0 * 256;
    const unsigned char* ab1 = AB + (r0 + 16) * 256;
    const int rsw = (r0 & 15);

#define COMPUTE(tt, buf) do {                                                        \
        const int k0_ = (tt) * 64;                                                   \
        const int aoff_ = ((((tt) >> 1) ^ rsw) << 4) + (((tt) & 1) << 3);            \
        unsigned long long au0 = *reinterpret_cast<const unsigned long long*>(ab0 + aoff_); \
        unsigned long long au1 = *reinterpret_cast<const unsigned long long*>(ab1 + aoff_); \
        _Pragma("unroll")                                                            \
        for (int kk = 0; kk < 2; ++kk) {                                             \
            const int gA = kk * 4 + q4;                                              \
            bf16x8 a0 = bits2bf16((unsigned)(au0 >> (gA * 8)) & 0xFFu);              \
            bf16x8 a1 = bits2bf16((unsigned)(au1 >> (gA * 8)) & 0xFFu);              \
            bf16x8 bb[4];                                                            \
            _Pragma("unroll")                                                        \
            for (int n = 0; n < 4; ++n) {                                            \
                int row = wc * 64 + n * 16 + l15;                                    \
                bb[n] = *reinterpret_cast<const bf16x8*>(                            \
                    &(buf)[row * 64 + ((gA ^ (row & 7)) * 8)]);                      \
            }                                                                        \
            bf16x8 be = *reinterpret_cast<const bf16x8*>(&Es[wc][k0_ + gA * 8]);     \
            __builtin_amdgcn_s_setprio(1);                                           \
            _Pragma("unroll")                                                        \
            for (int n = 0; n < 4; ++n) {                                            \
                acc[0][n] = __builtin_amdgcn_mfma_f32_16x16x32_bf16(a0, bb[n], acc[0][n], 0, 0, 0); \
                acc[1][n] = __builtin_amdgcn_mfma_f32_16x16x32_bf16(a1, bb[n], acc[1][n], 0, 0, 0); \
            }                                                                        \
            accd[0] = __builtin_amdgcn_mfma_f32_16x16x32_bf16(a0, be, accd[0], 0, 0, 0); \
            accd[1] = __builtin_amdgcn_mfma_f32_16x16x32_bf16(a1, be, accd[1], 0, 0, 0); \
            __builtin_amdgcn_s_setprio(0);                                           \
        }                                                                            \
    } while (0)

    for (int t = 0; t < 30; ++t) {
        STAGE_B(bufC, t * 64 + 128);   // stage t+2
        COMPUTE(t, bufA);
        WAITV2();                      // own loads of tile t+1 done
        BAR();                         // everyone done reading bufA & loads visible
        short* tmp = bufA; bufA = bufB; bufB = bufC; bufC = tmp;
    }
    COMPUTE(30, bufA);
    WAITV0();
    BAR();
    COMPUTE(31, bufB);

    // ---- epilogue: out = num / den (den held by the same lane) ----
    float* obase = out + ((size_t)b * N_ + m0) * C_ + n0 + wc * 64;
#pragma unroll
    for (int m = 0; m < 2; ++m) {
        int rbase = wr * 32 + m * 16 + q4 * 4;
        float inv[4];
#pragma unroll
        for (int r = 0; r < 4; ++r) inv[r] = 1.0f / accd[m][r];
#pragma unroll
        for (int n = 0; n < 4; ++n) {
            int gc = n * 16 + l15;
#pragma unroll
            for (int r = 0; r < 4; ++r)
                obase[(size_t)(rbase + r) * C_ + gc] = acc[m][n][r] * inv[r];
        }
    }
#undef STAGE_B
#undef COMPUTE
}

// ---------------------------------------------------------------------------
extern "C" void kernel_launch(void* const* d_in, const int* in_sizes, int n_in,
                              void* d_out, int out_size, void* d_ws, size_t ws_size,
                              hipStream_t stream) {
    const float* x        = (const float*)d_in[0];
    const int*   adj      = (const int*)d_in[1];
    const float* weight   = (const float*)d_in[2];
    // d_in[3] = attn_src : unused (cancels in softmax over neighbors j)
    const float* attn_dst = (const float*)d_in[4];
    float* out = (float*)d_out;

    // workspace:
    //   xb  : 4 MiB bf16
    //   wbT : 256 KiB bf16
    //   ebT : 128 KiB bf16   [b][h][j]
    //   gT  : 8 MiB bf16     [b][c][j]
    //   bm  : 2 MiB bitmask  [b*N + i][N/8 bytes]
    short* xb  = (short*)d_ws;
    short* wbT = xb + (size_t)B_ * N_ * INF_;
    short* ebT = wbT + (size_t)C_ * INF_;
    short* gT  = ebT + (size_t)B_ * H_ * N_;
    unsigned char* bmp = (unsigned char*)(gT + (size_t)B_ * C_ * N_);

    // 1. fused pack (adj->bits) + casts (x->xb, W->wbT)
    cast_kernel<<<dim3(2048 + 1024 + 32), 256, 0, stream>>>(x, weight, adj, xb, wbT, bmp);
    // 2. fused projection + e + gT
    proj_fused<<<dim3((B_ * N_) / 128, C_ / 64), 256, 0, stream>>>(xb, wbT, attn_dst, ebT, gT);
    // 3. numerator GEMM + denominator (MFMA pipeline) + divide -> out
    agg_mfma<<<dim3(256), 512, 0, stream>>>(bmp, gT, ebT, out);
}

// Round 9
// 58.506 us; speedup vs baseline: 1.2529x; 1.1462x over previous
//
#include <hip/hip_runtime.h>
#include <hip/hip_bf16.h>
#include <math.h>

#define B_    4
#define N_    2048
#define INF_  256
#define OUTF_ 64
#define H_    8
#define C_    512   // H_*OUTF_

typedef __attribute__((ext_vector_type(8))) short  bf16x8;
typedef __attribute__((ext_vector_type(4))) short  s16x4;
typedef __attribute__((ext_vector_type(4))) float  f32x4;

static __device__ __forceinline__ short f2b(float f) {
    union { float f; unsigned u; } v; v.f = f;
    unsigned r = (v.u + 0x7FFFu + ((v.u >> 16) & 1u)) >> 16;  // RNE
    return (short)r;
}
static __device__ __forceinline__ float b2f(short s) {
    union { unsigned u; float f; } v; v.u = ((unsigned)(unsigned short)s) << 16;
    return v.f;
}

#define GL2LDS(gsrc, ldst)                                                          \
    __builtin_amdgcn_global_load_lds(                                               \
        (const __attribute__((address_space(1))) void*)(gsrc),                      \
        (__attribute__((address_space(3))) void*)(ldst), 16, 0, 0)

#define WAITV4() asm volatile("s_waitcnt vmcnt(4)" ::: "memory")
#define WAITV2() asm volatile("s_waitcnt vmcnt(2)" ::: "memory")
#define WAITV0() asm volatile("s_waitcnt vmcnt(0)" ::: "memory")
#define WAITLG() asm volatile("s_waitcnt lgkmcnt(0)" ::: "memory")
#define BAR()    do { asm volatile("" ::: "memory"); __builtin_amdgcn_s_barrier(); \
                      asm volatile("" ::: "memory"); } while (0)

// ---------------------------------------------------------------------------
// Kernel 1: fused pack + casts (one launch).
//   blocks [0,2048):       adj -> bitmask bm (1 bit per edge; wave ballot)
//   blocks [2048,3072):    x -> xb (bf16)
//   blocks [3072,3104):    W[256][512] -> wbT[512][256] (bf16 transposed)
// ---------------------------------------------------------------------------
__global__ __launch_bounds__(256)
void cast_kernel(const float* __restrict__ x, const float* __restrict__ w,
                 const int* __restrict__ adj,
                 short* __restrict__ xb, short* __restrict__ wbT,
                 unsigned char* __restrict__ bm) {
    __shared__ short T[64][72];
    const int bid = blockIdx.x;
    if (bid < 2048) {
        const int wid  = threadIdx.x >> 6;
        const int lane = threadIdx.x & 63;
        const int row  = bid * 4 + wid;           // 0..8191 (= b*N + i)
        const int* arow = adj + (size_t)row * N_;
        unsigned long long myword = 0;
#pragma unroll
        for (int it = 0; it < 32; ++it) {
            int v = arow[it * 64 + lane];
            unsigned long long m = __ballot(v != 0);
            if (lane == it) myword = m;
        }
        if (lane < 32)
            *reinterpret_cast<unsigned long long*>(bm + (size_t)row * 256 + lane * 8) = myword;
    } else if (bid < 3072) {
        size_t i8 = (size_t)(bid - 2048) * 256 + threadIdx.x;
        const float4* p = reinterpret_cast<const float4*>(x + i8 * 8);
        float4 v0 = p[0], v1 = p[1];
        bf16x8 o;
        o[0] = f2b(v0.x); o[1] = f2b(v0.y); o[2] = f2b(v0.z); o[3] = f2b(v0.w);
        o[4] = f2b(v1.x); o[5] = f2b(v1.y); o[6] = f2b(v1.z); o[7] = f2b(v1.w);
        *reinterpret_cast<bf16x8*>(xb + i8 * 8) = o;
    } else {
        int blk = bid - 3072;                 // 32 blocks: 8 c-tiles x 4 k-tiles
        int c0 = (blk & 7) * 64;
        int k0 = (blk >> 3) * 64;
        int t = threadIdx.x;
        int cl = (t & 15) * 4;
#pragma unroll
        for (int p = 0; p < 4; ++p) {
            int kl = p * 16 + (t >> 4);
            float4 v = *reinterpret_cast<const float4*>(&w[(size_t)(k0 + kl) * C_ + c0 + cl]);
            T[cl + 0][kl] = f2b(v.x);
            T[cl + 1][kl] = f2b(v.y);
            T[cl + 2][kl] = f2b(v.z);
            T[cl + 3][kl] = f2b(v.w);
        }
        __syncthreads();
        int cr = t >> 2;
        int ks = (t & 3) * 16;
        short* dst = &wbT[(size_t)(c0 + cr) * INF_ + k0 + ks];
        *reinterpret_cast<bf16x8*>(dst)     = *reinterpret_cast<const bf16x8*>(&T[cr][ks]);
        *reinterpret_cast<bf16x8*>(dst + 8) = *reinterpret_cast<const bf16x8*>(&T[cr][ks + 8]);
    }
}

// ---------------------------------------------------------------------------
// Kernel 2: fused projection (bf16 MFMA) + e + gT.  (unchanged, validated)
// ---------------------------------------------------------------------------
__global__ __launch_bounds__(256)
void proj_fused(const short* __restrict__ xb, const short* __restrict__ wbT,
                const float* __restrict__ attn_dst,
                short* __restrict__ ebT, short* __restrict__ gT) {
    __shared__ char smem[24576];
    short* As = (short*)smem;                  // 16 KiB  [128][64] swizzled
    short* Bs = (short*)(smem + 16384);        //  8 KiB  [64][64]  swizzled
    short* Tt = (short*)smem;                  // 64 x 136 bf16 = 17408 B
    float* Sr = (float*)(smem + 17408);        // 2 x 128 f32   = 1024 B
    short* Eb = (short*)(smem + 18432);        // 128 bf16      = 256 B

    const int m0 = blockIdx.x * 128;
    const int n0 = blockIdx.y * 64;
    const int head = n0 >> 6;
    const int b    = m0 >> 11;
    const int j0g  = m0 & (N_ - 1);
    const int wid  = threadIdx.x >> 6;
    const int lane = threadIdx.x & 63;
    const int wr = wid >> 1, wc = wid & 1;
    const int q4 = lane >> 4, l15 = lane & 15;
    const int lr = lane >> 3;
    const int ls = (lane & 7) ^ lr;
    const short* Abase = xb + (size_t)m0 * INF_;
    const short* Bbase = wbT + (size_t)n0 * INF_;

    f32x4 acc[4][2];
#pragma unroll
    for (int m = 0; m < 4; ++m)
#pragma unroll
        for (int n = 0; n < 2; ++n) acc[m][n] = (f32x4){0.f, 0.f, 0.f, 0.f};

    for (int k0 = 0; k0 < INF_; k0 += 64) {
#pragma unroll
        for (int q = 0; q < 4; ++q) {
            int chunk = wid * 4 + q;
            int row   = chunk * 8 + lr;
            GL2LDS(Abase + (size_t)row * INF_ + k0 + ls * 8, As + chunk * 512);
        }
#pragma unroll
        for (int q = 0; q < 2; ++q) {
            int chunk = wid * 2 + q;
            int row   = chunk * 8 + lr;
            GL2LDS(Bbase + (size_t)row * INF_ + k0 + ls * 8, Bs + chunk * 512);
        }
        __syncthreads();
#pragma unroll
        for (int kk = 0; kk < 2; ++kk) {
            const int ko = kk * 32 + q4 * 8;
            bf16x8 a[4], bb[2];
#pragma unroll
            for (int m = 0; m < 4; ++m) {
                int row = wr * 64 + m * 16 + l15;
                a[m] = *reinterpret_cast<const bf16x8*>(&As[row * 64 + (ko ^ ((row & 7) * 8))]);
            }
#pragma unroll
            for (int n = 0; n < 2; ++n) {
                int row = wc * 32 + n * 16 + l15;
                bb[n] = *reinterpret_cast<const bf16x8*>(&Bs[row * 64 + (ko ^ ((row & 7) * 8))]);
            }
#pragma unroll
            for (int m = 0; m < 4; ++m)
#pragma unroll
                for (int n = 0; n < 2; ++n)
                    acc[m][n] = __builtin_amdgcn_mfma_f32_16x16x32_bf16(a[m], bb[n], acc[m][n], 0, 0, 0);
        }
        __syncthreads();
    }

    float af0 = attn_dst[head * 64 + wc * 32 + l15];
    float af1 = attn_dst[head * 64 + wc * 32 + 16 + l15];
#pragma unroll
    for (int m = 0; m < 4; ++m) {
        f32x4 part;
#pragma unroll
        for (int r = 0; r < 4; ++r)
            part[r] = acc[m][0][r] * af0 + acc[m][1][r] * af1;
#pragma unroll
        for (int off = 1; off < 16; off <<= 1)
#pragma unroll
            for (int r = 0; r < 4; ++r) part[r] += __shfl_xor(part[r], off);
        if (l15 == 0)
            *reinterpret_cast<f32x4*>(&Sr[wc * 128 + wr * 64 + m * 16 + q4 * 4]) = part;
    }
    __syncthreads();
    const int t = threadIdx.x;
    if (t < 128) {
        float s = Sr[t] + Sr[128 + t];
        short eb = f2b(expf(s));
        Eb[t] = eb;
        ebT[((size_t)b * H_ + head) * N_ + j0g + t] = eb;
    }
    __syncthreads();
#pragma unroll
    for (int m = 0; m < 4; ++m) {
        int jl = wr * 64 + m * 16 + q4 * 4;
        float ev[4];
#pragma unroll
        for (int r = 0; r < 4; ++r) ev[r] = b2f(Eb[jl + r]);
#pragma unroll
        for (int n = 0; n < 2; ++n) {
            int cl = wc * 32 + n * 16 + l15;
            s16x4 gv;
#pragma unroll
            for (int r = 0; r < 4; ++r) gv[r] = f2b(acc[m][n][r] * ev[r]);
            *reinterpret_cast<s16x4*>(&Tt[cl * 136 + jl]) = gv;
        }
    }
    __syncthreads();
    {
        int c  = t >> 2;
        int jc = (t & 3) * 32;
        short* dst = &gT[((size_t)b * C_ + n0 + c) * N_ + j0g + jc];
#pragma unroll
        for (int u = 0; u < 4; ++u)
            *reinterpret_cast<bf16x8*>(dst + u * 8) =
                *reinterpret_cast<const bf16x8*>(&Tt[c * 136 + jc + u * 8]);
    }
}

// ---------------------------------------------------------------------------
// Kernel 3: numerator GEMM (bf16 MFMA) + denominator + divide.
// BM=128, BN=128 (2 heads), 8 waves (4m x 2n), wave tile 32x64.
// adj-bits (32 KB, 16B-XOR-swizzled) + e rows (8 KB) staged to LDS once.
// B (gT): 4-buffer counted-vmcnt pipeline (depth 3; steady-state vmcnt(4)
// leaves tiles t+2,t+3 in flight with t+1 complete; per-wave wait + barrier
// => all waves' loads visible).
// A bits -> bf16 via 16-entry x 8B nibble LUT in LDS: entries never share a
// bank (128 B spans 32 banks exactly) => conflict-free ds_read_b64 for any
// byte pattern; replaces ~28 VALU/byte packing with 2 LDS reads.
// den per wave in-register (lane holding num[row,col] also holds den[row]).
// ---------------------------------------------------------------------------
__global__ __launch_bounds__(512, 2)
void agg_mfma(const unsigned char* __restrict__ bm, const short* __restrict__ gT,
              const short* __restrict__ ebT, float* __restrict__ out) {
    __shared__ short Bs[4][8192];          // 4 x 16 KiB : [c 0..127][k 0..63] swizzled
    __shared__ unsigned char AB[32768];    // adj bits: 128 rows x 256 B, 16B-swizzled
    __shared__ short Es[2][2048];          // e rows of the block's 2 heads
    __shared__ short LUT[64];              // 16 nibble entries x 4 bf16 (8 B)

    // XCD-chunked swizzle: 256 blocks -> 8 chunks of 32 (same gT n-panel/XCD)
    const int work = (blockIdx.x & 7) * 32 + (blockIdx.x >> 3);
    const int mt = work & 15;
    const int nt = (work >> 4) & 3;
    const int b  = work >> 6;
    const int m0 = mt * 128;
    const int n0 = nt * 128;
    const int h0 = n0 >> 6;

    const int tid  = threadIdx.x;
    const int wid  = tid >> 6;
    const int lane = tid & 63;
    const int wr = wid >> 1, wc = wid & 1;
    const int q4 = lane >> 4, l15 = lane & 15;
    const int lr = lane >> 3;
    const int ls = (lane & 7) ^ lr;

    if (tid < 64)
        LUT[tid] = ((((tid >> 2)) >> (tid & 3)) & 1) ? (short)0x3F80 : (short)0;

    const short* Bbase = gT + ((size_t)b * C_ + n0) * N_;

    // ---- prologue staging (order matters for vmcnt accounting) ----
    {   // adj bits: 4 x (1 KB per wave); lds[row][w16] <- gbl[row][w16 ^ (row&15)]
        const unsigned char* bmb = bm + ((size_t)b * N_ + m0) * 256;
#pragma unroll
        for (int p = 0; p < 4; ++p) {
            int row = p * 32 + wid * 4 + (lane >> 4);
            GL2LDS(bmb + (size_t)row * 256 + (((lane & 15) ^ (row & 15)) << 4),
                   AB + p * 8192 + wid * 1024);
        }
    }
    // e rows: head = wid>>2, quarter = wid&3
    GL2LDS(ebT + ((size_t)b * H_ + h0 + (wid >> 2)) * N_ + (wid & 3) * 512 + lane * 8,
           (short*)Es + wid * 512);

#define STAGE_B(buf, k0s) do {                                                       \
        GL2LDS(Bbase + (size_t)(wid * 16 + lr) * N_ + (k0s) + ls * 8,                \
               (buf) + wid * 1024);                                                  \
        GL2LDS(Bbase + (size_t)(wid * 16 + 8 + lr) * N_ + (k0s) + ls * 8,            \
               (buf) + wid * 1024 + 512);                                            \
    } while (0)

    f32x4 acc[2][4];
    f32x4 accd[2];
#pragma unroll
    for (int m = 0; m < 2; ++m) {
        accd[m] = (f32x4){0.f, 0.f, 0.f, 0.f};
#pragma unroll
        for (int n = 0; n < 4; ++n) acc[m][n] = (f32x4){0.f, 0.f, 0.f, 0.f};
    }

    short* bufA = &Bs[0][0];
    short* bufB = &Bs[1][0];
    short* bufC = &Bs[2][0];
    short* bufD = &Bs[3][0];
    STAGE_B(bufA, 0);
    STAGE_B(bufB, 64);
    STAGE_B(bufC, 128);
    WAITLG();          // LUT ds_writes retired before barrier
    WAITV4();          // AB(4)+E(1)+B0(2) retired; B1/B2 (4) may be in flight
    BAR();

    const int r0  = wr * 32 + l15;
    const unsigned char* ab0 = AB + r0 * 256;
    const unsigned char* ab1 = AB + (r0 + 16) * 256;
    const int rsw = (r0 & 15);

#define EXPAND(byte_) ({                                                             \
        union { bf16x8 v_; unsigned long long q_[2]; } u_;                           \
        u_.q_[0] = *reinterpret_cast<const unsigned long long*>(&LUT[((byte_) & 15u) * 4]); \
        u_.q_[1] = *reinterpret_cast<const unsigned long long*>(&LUT[(((byte_) >> 4) & 15u) * 4]); \
        u_.v_; })

#define COMPUTE(tt, buf) do {                                                        \
        const int k0_ = (tt) * 64;                                                   \
        const int aoff_ = ((((tt) >> 1) ^ rsw) << 4) + (((tt) & 1) << 3);            \
        unsigned long long au0 = *reinterpret_cast<const unsigned long long*>(ab0 + aoff_); \
        unsigned long long au1 = *reinterpret_cast<const unsigned long long*>(ab1 + aoff_); \
        _Pragma("unroll")                                                            \
        for (int kk = 0; kk < 2; ++kk) {                                             \
            const int gA = kk * 4 + q4;                                              \
            unsigned by0_ = (unsigned)(au0 >> (gA * 8)) & 0xFFu;                     \
            unsigned by1_ = (unsigned)(au1 >> (gA * 8)) & 0xFFu;                     \
            bf16x8 a0 = EXPAND(by0_);                                                \
            bf16x8 a1 = EXPAND(by1_);                                                \
            bf16x8 bb[4];                                                            \
            _Pragma("unroll")                                                        \
            for (int n = 0; n < 4; ++n) {                                            \
                int row = wc * 64 + n * 16 + l15;                                    \
                bb[n] = *reinterpret_cast<const bf16x8*>(                            \
                    &(buf)[row * 64 + ((gA ^ (row & 7)) * 8)]);                      \
            }                                                                        \
            bf16x8 be = *reinterpret_cast<const bf16x8*>(&Es[wc][k0_ + gA * 8]);     \
            _Pragma("unroll")                                                        \
            for (int n = 0; n < 4; ++n) {                                            \
                acc[0][n] = __builtin_amdgcn_mfma_f32_16x16x32_bf16(a0, bb[n], acc[0][n], 0, 0, 0); \
                acc[1][n] = __builtin_amdgcn_mfma_f32_16x16x32_bf16(a1, bb[n], acc[1][n], 0, 0, 0); \
            }                                                                        \
            accd[0] = __builtin_amdgcn_mfma_f32_16x16x32_bf16(a0, be, accd[0], 0, 0, 0); \
            accd[1] = __builtin_amdgcn_mfma_f32_16x16x32_bf16(a1, be, accd[1], 0, 0, 0); \
        }                                                                            \
    } while (0)

    for (int t = 0; t < 29; ++t) {
        STAGE_B(bufD, t * 64 + 192);   // stage tile t+3
        COMPUTE(t, bufA);
        WAITV4();                      // tile t+1 loads complete (t+2,t+3 in flight)
        BAR();                         // all waves' loads visible; bufA free
        short* tmp = bufA; bufA = bufB; bufB = bufC; bufC = bufD; bufD = tmp;
    }
    COMPUTE(29, bufA);
    WAITV2();
    BAR();
    COMPUTE(30, bufB);
    WAITV0();
    BAR();
    COMPUTE(31, bufC);

    // ---- epilogue: out = num / den (den held by the same lane) ----
    float* obase = out + ((size_t)b * N_ + m0) * C_ + n0 + wc * 64;
#pragma unroll
    for (int m = 0; m < 2; ++m) {
        int rbase = wr * 32 + m * 16 + q4 * 4;
        float inv[4];
#pragma unroll
        for (int r = 0; r < 4; ++r) inv[r] = 1.0f / accd[m][r];
#pragma unroll
        for (int n = 0; n < 4; ++n) {
            int gc = n * 16 + l15;
#pragma unroll
            for (int r = 0; r < 4; ++r)
                obase[(size_t)(rbase + r) * C_ + gc] = acc[m][n][r] * inv[r];
        }
    }
#undef STAGE_B
#undef COMPUTE
#undef EXPAND
}

// ---------------------------------------------------------------------------
extern "C" void kernel_launch(void* const* d_in, const int* in_sizes, int n_in,
                              void* d_out, int out_size, void* d_ws, size_t ws_size,
                              hipStream_t stream) {
    const float* x        = (const float*)d_in[0];
    const int*   adj      = (const int*)d_in[1];
    const float* weight   = (const float*)d_in[2];
    // d_in[3] = attn_src : unused (cancels in softmax over neighbors j)
    const float* attn_dst = (const float*)d_in[4];
    float* out = (float*)d_out;

    // workspace:
    //   xb  : 4 MiB bf16
    //   wbT : 256 KiB bf16
    //   ebT : 128 KiB bf16   [b][h][j]
    //   gT  : 8 MiB bf16     [b][c][j]
    //   bm  : 2 MiB bitmask  [b*N + i][N/8 bytes]
    short* xb  = (short*)d_ws;
    short* wbT = xb + (size_t)B_ * N_ * INF_;
    short* ebT = wbT + (size_t)C_ * INF_;
    short* gT  = ebT + (size_t)B_ * H_ * N_;
    unsigned char* bmp = (unsigned char*)(gT + (size_t)B_ * C_ * N_);

    // 1. fused pack (adj->bits) + casts (x->xb, W->wbT)
    cast_kernel<<<dim3(2048 + 1024 + 32), 256, 0, stream>>>(x, weight, adj, xb, wbT, bmp);
    // 2. fused projection + e + gT
    proj_fused<<<dim3((B_ * N_) / 128, C_ / 64), 256, 0, stream>>>(xb, wbT, attn_dst, ebT, gT);
    // 3. numerator GEMM + denominator (MFMA pipeline) + divide -> out
    agg_mfma<<<dim3(256), 512, 0, stream>>>(bmp, gT, ebT, out);
}

// Round 10
// 50.768 us; speedup vs baseline: 1.4438x; 1.1524x over previous
//
#include <hip/hip_runtime.h>
#include <hip/hip_bf16.h>
#include <math.h>

#define B_    4
#define N_    2048
#define INF_  256
#define OUTF_ 64
#define H_    8
#define C_    512   // H_*OUTF_

typedef __attribute__((ext_vector_type(8))) short  bf16x8;
typedef __attribute__((ext_vector_type(4))) short  s16x4;
typedef __attribute__((ext_vector_type(4))) float  f32x4;

static __device__ __forceinline__ short f2b(float f) {
    union { float f; unsigned u; } v; v.f = f;
    unsigned r = (v.u + 0x7FFFu + ((v.u >> 16) & 1u)) >> 16;  // RNE
    return (short)r;
}
static __device__ __forceinline__ float b2f(short s) {
    union { unsigned u; float f; } v; v.u = ((unsigned)(unsigned short)s) << 16;
    return v.f;
}
static __device__ __forceinline__ unsigned long long mk64(int lo, int hi) {
    return ((unsigned long long)(unsigned)hi << 32) | (unsigned)lo;
}

#define GL2LDS(gsrc, ldst)                                                          \
    __builtin_amdgcn_global_load_lds(                                               \
        (const __attribute__((address_space(1))) void*)(gsrc),                      \
        (__attribute__((address_space(3))) void*)(ldst), 16, 0, 0)

#define WAITV2() asm volatile("s_waitcnt vmcnt(2)" ::: "memory")
#define WAITV0() asm volatile("s_waitcnt vmcnt(0)" ::: "memory")
#define WAITLG() asm volatile("s_waitcnt lgkmcnt(0)" ::: "memory")
#define BAR()    do { asm volatile("" ::: "memory"); __builtin_amdgcn_s_barrier(); \
                      asm volatile("" ::: "memory"); } while (0)

// ---------------------------------------------------------------------------
// Kernel 1: small casts. blocks [0,1024): x -> xb (bf16).
// blocks [1024,1056): W[256][512] -> wbT[512][256] (bf16 transposed).
// ---------------------------------------------------------------------------
__global__ __launch_bounds__(256)
void cast_xw(const float* __restrict__ x, const float* __restrict__ w,
             short* __restrict__ xb, short* __restrict__ wbT) {
    __shared__ short T[64][72];
    const int bid = blockIdx.x;
    if (bid < 1024) {
        size_t i8 = (size_t)bid * 256 + threadIdx.x;
        const float4* p = reinterpret_cast<const float4*>(x + i8 * 8);
        float4 v0 = p[0], v1 = p[1];
        bf16x8 o;
        o[0] = f2b(v0.x); o[1] = f2b(v0.y); o[2] = f2b(v0.z); o[3] = f2b(v0.w);
        o[4] = f2b(v1.x); o[5] = f2b(v1.y); o[6] = f2b(v1.z); o[7] = f2b(v1.w);
        *reinterpret_cast<bf16x8*>(xb + i8 * 8) = o;
    } else {
        int blk = bid - 1024;                 // 32 blocks: 8 c-tiles x 4 k-tiles
        int c0 = (blk & 7) * 64;
        int k0 = (blk >> 3) * 64;
        int t = threadIdx.x;
        int cl = (t & 15) * 4;
#pragma unroll
        for (int p = 0; p < 4; ++p) {
            int kl = p * 16 + (t >> 4);
            float4 v = *reinterpret_cast<const float4*>(&w[(size_t)(k0 + kl) * C_ + c0 + cl]);
            T[cl + 0][kl] = f2b(v.x);
            T[cl + 1][kl] = f2b(v.y);
            T[cl + 2][kl] = f2b(v.z);
            T[cl + 3][kl] = f2b(v.w);
        }
        __syncthreads();
        int cr = t >> 2;
        int ks = (t & 3) * 16;
        short* dst = &wbT[(size_t)(c0 + cr) * INF_ + k0 + ks];
        *reinterpret_cast<bf16x8*>(dst)     = *reinterpret_cast<const bf16x8*>(&T[cr][ks]);
        *reinterpret_cast<bf16x8*>(dst + 8) = *reinterpret_cast<const bf16x8*>(&T[cr][ks + 8]);
    }
}

// ---------------------------------------------------------------------------
// Kernel 2: merged projection + adj pack (HBM stream overlaps MFMA compute).
//   bid&1==0 : proj block (validated proj_fused body), sub = bid>>1 (0..511)
//   bid&1==1 : pack block: 16 adj rows -> bitmask (wave ballot)
// ---------------------------------------------------------------------------
__global__ __launch_bounds__(256)
void proj_pack(const short* __restrict__ xb, const short* __restrict__ wbT,
               const float* __restrict__ attn_dst, const int* __restrict__ adj,
               short* __restrict__ ebT, short* __restrict__ gT,
               unsigned char* __restrict__ bm) {
    __shared__ char smem[24576];
    const int sub = blockIdx.x >> 1;
    if (blockIdx.x & 1) {
        // ---- pack: rows sub*16 .. +15 ----
        const int wid  = threadIdx.x >> 6;
        const int lane = threadIdx.x & 63;
        const int rowbase = sub * 16 + wid * 4;
#pragma unroll
        for (int rr = 0; rr < 4; ++rr) {
            const int row = rowbase + rr;
            const int* arow = adj + (size_t)row * N_;
            unsigned long long myword = 0;
#pragma unroll
            for (int it = 0; it < 32; ++it) {
                unsigned long long m = __ballot(arow[it * 64 + lane] != 0);
                if (lane == it) myword = m;
            }
            if (lane < 32)
                *reinterpret_cast<unsigned long long*>(bm + (size_t)row * 256 + lane * 8) = myword;
        }
        return;
    }
    // ---- proj (unchanged, validated) ----
    short* As = (short*)smem;                  // 16 KiB  [128][64] swizzled
    short* Bs = (short*)(smem + 16384);        //  8 KiB  [64][64]  swizzled
    short* Tt = (short*)smem;                  // 64 x 136 bf16 = 17408 B
    float* Sr = (float*)(smem + 17408);        // 2 x 128 f32   = 1024 B
    short* Eb = (short*)(smem + 18432);        // 128 bf16      = 256 B

    const int m0 = (sub & 63) * 128;
    const int n0 = (sub >> 6) * 64;
    const int head = n0 >> 6;
    const int b    = m0 >> 11;
    const int j0g  = m0 & (N_ - 1);
    const int wid  = threadIdx.x >> 6;
    const int lane = threadIdx.x & 63;
    const int wr = wid >> 1, wc = wid & 1;
    const int q4 = lane >> 4, l15 = lane & 15;
    const int lr = lane >> 3;
    const int ls = (lane & 7) ^ lr;
    const short* Abase = xb + (size_t)m0 * INF_;
    const short* Bbase = wbT + (size_t)n0 * INF_;

    f32x4 acc[4][2];
#pragma unroll
    for (int m = 0; m < 4; ++m)
#pragma unroll
        for (int n = 0; n < 2; ++n) acc[m][n] = (f32x4){0.f, 0.f, 0.f, 0.f};

    for (int k0 = 0; k0 < INF_; k0 += 64) {
#pragma unroll
        for (int q = 0; q < 4; ++q) {
            int chunk = wid * 4 + q;
            int row   = chunk * 8 + lr;
            GL2LDS(Abase + (size_t)row * INF_ + k0 + ls * 8, As + chunk * 512);
        }
#pragma unroll
        for (int q = 0; q < 2; ++q) {
            int chunk = wid * 2 + q;
            int row   = chunk * 8 + lr;
            GL2LDS(Bbase + (size_t)row * INF_ + k0 + ls * 8, Bs + chunk * 512);
        }
        __syncthreads();
#pragma unroll
        for (int kk = 0; kk < 2; ++kk) {
            const int ko = kk * 32 + q4 * 8;
            bf16x8 a[4], bb[2];
#pragma unroll
            for (int m = 0; m < 4; ++m) {
                int row = wr * 64 + m * 16 + l15;
                a[m] = *reinterpret_cast<const bf16x8*>(&As[row * 64 + (ko ^ ((row & 7) * 8))]);
            }
#pragma unroll
            for (int n = 0; n < 2; ++n) {
                int row = wc * 32 + n * 16 + l15;
                bb[n] = *reinterpret_cast<const bf16x8*>(&Bs[row * 64 + (ko ^ ((row & 7) * 8))]);
            }
#pragma unroll
            for (int m = 0; m < 4; ++m)
#pragma unroll
                for (int n = 0; n < 2; ++n)
                    acc[m][n] = __builtin_amdgcn_mfma_f32_16x16x32_bf16(a[m], bb[n], acc[m][n], 0, 0, 0);
        }
        __syncthreads();
    }

    float af0 = attn_dst[head * 64 + wc * 32 + l15];
    float af1 = attn_dst[head * 64 + wc * 32 + 16 + l15];
#pragma unroll
    for (int m = 0; m < 4; ++m) {
        f32x4 part;
#pragma unroll
        for (int r = 0; r < 4; ++r)
            part[r] = acc[m][0][r] * af0 + acc[m][1][r] * af1;
#pragma unroll
        for (int off = 1; off < 16; off <<= 1)
#pragma unroll
            for (int r = 0; r < 4; ++r) part[r] += __shfl_xor(part[r], off);
        if (l15 == 0)
            *reinterpret_cast<f32x4*>(&Sr[wc * 128 + wr * 64 + m * 16 + q4 * 4]) = part;
    }
    __syncthreads();
    const int t = threadIdx.x;
    if (t < 128) {
        float s = Sr[t] + Sr[128 + t];
        short eb = f2b(expf(s));
        Eb[t] = eb;
        ebT[((size_t)b * H_ + head) * N_ + j0g + t] = eb;
    }
    __syncthreads();
#pragma unroll
    for (int m = 0; m < 4; ++m) {
        int jl = wr * 64 + m * 16 + q4 * 4;
        float ev[4];
#pragma unroll
        for (int r = 0; r < 4; ++r) ev[r] = b2f(Eb[jl + r]);
#pragma unroll
        for (int n = 0; n < 2; ++n) {
            int cl = wc * 32 + n * 16 + l15;
            s16x4 gv;
#pragma unroll
            for (int r = 0; r < 4; ++r) gv[r] = f2b(acc[m][n][r] * ev[r]);
            *reinterpret_cast<s16x4*>(&Tt[cl * 136 + jl]) = gv;
        }
    }
    __syncthreads();
    {
        int c  = t >> 2;
        int jc = (t & 3) * 32;
        short* dst = &gT[((size_t)b * C_ + n0 + c) * N_ + j0g + jc];
#pragma unroll
        for (int u = 0; u < 4; ++u)
            *reinterpret_cast<bf16x8*>(dst + u * 8) =
                *reinterpret_cast<const bf16x8*>(&Tt[c * 136 + jc + u * 8]);
    }
}

// ---------------------------------------------------------------------------
// Kernel 3: numerator GEMM (bf16 MFMA) + denominator + divide.
// BM=128, BN=64, 8 waves (4m x 2n), wave tile 32x32. Grid 512 = 2 blocks/CU.
// Phases of K=128 (2 tiles) -> 16 barriers. 3 LDS buffer-pairs (48 KB),
// counted vmcnt: in-loop vmcnt(2) retires everything but the 2 newest loads,
// guaranteeing the pair for phase p+1 is resident (prologue drains with
// vmcnt(0) once, robust to GL2LDS issue reordering).
// A bits: per-lane int4 global loads (L1/L2-hit), prefetched one phase ahead;
// expansion via the 16x8B nibble LUT (bank-conflict-free by construction).
// den: wave (wr,wc) computes rows wc-half via 1 MFMA/kk; Dr LDS exchange.
// ---------------------------------------------------------------------------
__global__ __launch_bounds__(512, 4)
void agg_mfma(const unsigned char* __restrict__ bm, const short* __restrict__ gT,
              const short* __restrict__ ebT, float* __restrict__ out) {
    __shared__ short Bs[6][4096];       // 3 pairs x 2 tiles x 8 KiB = 48 KiB
    __shared__ short Es[2048];          // 4 KiB : e row of this head
    __shared__ float Dr[128];
    __shared__ short LUT[64];           // 16 nibble entries x 4 bf16

    // XCD-chunked swizzle: 512 blocks -> 8 chunks of 64 (same b / few panels)
    const int work = (blockIdx.x & 7) * 64 + (blockIdx.x >> 3);
    const int mt = work & 15;
    const int nt = (work >> 4) & 7;
    const int b  = work >> 7;
    const int m0 = mt * 128;
    const int n0 = nt * 64;

    const int tid  = threadIdx.x;
    const int wid  = tid >> 6;
    const int lane = tid & 63;
    const int wr = wid >> 1, wc = wid & 1;   // 4m x 2n
    const int q4 = lane >> 4, l15 = lane & 15;
    const int lr = lane >> 3;
    const int ls = (lane & 7) ^ lr;

    if (tid < 64)
        LUT[tid] = ((((tid >> 2)) >> (tid & 3)) & 1) ? (short)0x3F80 : (short)0;

    const short* Bbase = gT + ((size_t)b * C_ + n0) * N_;
    const unsigned char* M0 = bm + ((size_t)b * N_ + m0 + wr * 32 + l15) * 256;
    const unsigned char* M1 = M0 + 16 * 256;

#define STAGE1(buf, k0s) \
    GL2LDS(Bbase + (size_t)(wid * 8 + lr) * N_ + (k0s) + ls * 8, (buf) + wid * 512)

#define EXPAND(byte_) ({                                                             \
        union { bf16x8 v_; unsigned long long q_[2]; } u_;                           \
        u_.q_[0] = *reinterpret_cast<const unsigned long long*>(&LUT[((byte_) & 15u) * 4]); \
        u_.q_[1] = *reinterpret_cast<const unsigned long long*>(&LUT[(((byte_) >> 4) & 15u) * 4]); \
        u_.v_; })

    f32x4 acc[2][2];
    f32x4 accd = (f32x4){0.f, 0.f, 0.f, 0.f};
#pragma unroll
    for (int m = 0; m < 2; ++m)
#pragma unroll
        for (int n = 0; n < 2; ++n) acc[m][n] = (f32x4){0.f, 0.f, 0.f, 0.f};

#define COMPUTE_T(bufp, k0_, abits0, abits1) do {                                    \
        _Pragma("unroll")                                                            \
        for (int kk = 0; kk < 2; ++kk) {                                             \
            const int gA = kk * 4 + q4;                                              \
            bf16x8 a0 = EXPAND((unsigned)((abits0) >> (gA * 8)) & 0xFFu);            \
            bf16x8 a1 = EXPAND((unsigned)((abits1) >> (gA * 8)) & 0xFFu);            \
            bf16x8 b0, b1, be;                                                       \
            { int row = wc * 32 + l15;                                               \
              b0 = *reinterpret_cast<const bf16x8*>(&(bufp)[row * 64 + ((gA ^ (row & 7)) * 8)]); } \
            { int row = wc * 32 + 16 + l15;                                          \
              b1 = *reinterpret_cast<const bf16x8*>(&(bufp)[row * 64 + ((gA ^ (row & 7)) * 8)]); } \
            be = *reinterpret_cast<const bf16x8*>(&Es[(k0_) + gA * 8]);              \
            acc[0][0] = __builtin_amdgcn_mfma_f32_16x16x32_bf16(a0, b0, acc[0][0], 0, 0, 0); \
            acc[0][1] = __builtin_amdgcn_mfma_f32_16x16x32_bf16(a0, b1, acc[0][1], 0, 0, 0); \
            acc[1][0] = __builtin_amdgcn_mfma_f32_16x16x32_bf16(a1, b0, acc[1][0], 0, 0, 0); \
            acc[1][1] = __builtin_amdgcn_mfma_f32_16x16x32_bf16(a1, b1, acc[1][1], 0, 0, 0); \
            accd = __builtin_amdgcn_mfma_f32_16x16x32_bf16(wc ? a1 : a0, be, accd, 0, 0, 0); \
        }                                                                            \
    } while (0)

    // ---- prologue: au(0), Es, pairs 0 & 1 ----
    int4 a0c = *reinterpret_cast<const int4*>(M0);
    int4 a1c = *reinterpret_cast<const int4*>(M1);
    if (wid < 4)
        GL2LDS(ebT + ((size_t)b * H_ + nt) * N_ + wid * 512 + lane * 8, Es + wid * 512);
    short *cA = &Bs[0][0], *cB = &Bs[1][0];
    short *nA = &Bs[2][0], *nB = &Bs[3][0];
    short *sA = &Bs[4][0], *sB = &Bs[5][0];
    STAGE1(cA, 0);
    STAGE1(cB, 64);
    STAGE1(nA, 128);
    STAGE1(nB, 192);
    WAITLG();          // LUT ds_writes retired
    WAITV0();          // everything resident (one-time drain)
    BAR();

    int4 a0n, a1n;
    for (int p = 0; p < 14; ++p) {
        a0n = *reinterpret_cast<const int4*>(M0 + (p + 1) * 16);
        a1n = *reinterpret_cast<const int4*>(M1 + (p + 1) * 16);
        STAGE1(sA, p * 128 + 256);     // pair p+2, tile 0
        STAGE1(sB, p * 128 + 320);     // pair p+2, tile 1
        COMPUTE_T(cA, p * 128,      mk64(a0c.x, a0c.y), mk64(a1c.x, a1c.y));
        COMPUTE_T(cB, p * 128 + 64, mk64(a0c.z, a0c.w), mk64(a1c.z, a1c.w));
        WAITV2();                      // pair p+1 resident (all but 2 newest retired)
        BAR();
        short* t0 = cA; short* t1 = cB;
        cA = nA; cB = nB; nA = sA; nB = sB; sA = t0; sB = t1;
        a0c = a0n; a1c = a1n;
    }
    // p = 14
    a0n = *reinterpret_cast<const int4*>(M0 + 15 * 16);
    a1n = *reinterpret_cast<const int4*>(M1 + 15 * 16);
    COMPUTE_T(cA, 14 * 128,      mk64(a0c.x, a0c.y), mk64(a1c.x, a1c.y));
    COMPUTE_T(cB, 14 * 128 + 64, mk64(a0c.z, a0c.w), mk64(a1c.z, a1c.w));
    WAITV0();
    BAR();
    cA = nA; cB = nB; a0c = a0n; a1c = a1n;
    // p = 15
    COMPUTE_T(cA, 15 * 128,      mk64(a0c.x, a0c.y), mk64(a1c.x, a1c.y));
    COMPUTE_T(cB, 15 * 128 + 64, mk64(a0c.z, a0c.w), mk64(a1c.z, a1c.w));

    // ---- den exchange + epilogue ----
    if (l15 == 0)
        *reinterpret_cast<f32x4*>(&Dr[wr * 32 + wc * 16 + q4 * 4]) = accd;
    __syncthreads();

    float* obase = out + ((size_t)b * N_ + m0) * C_ + n0;
#pragma unroll
    for (int m = 0; m < 2; ++m) {
        int rbase = wr * 32 + m * 16 + q4 * 4;
        float inv[4];
#pragma unroll
        for (int r = 0; r < 4; ++r) inv[r] = 1.0f / Dr[rbase + r];
#pragma unroll
        for (int n = 0; n < 2; ++n) {
            int gc = wc * 32 + n * 16 + l15;
#pragma unroll
            for (int r = 0; r < 4; ++r)
                obase[(size_t)(rbase + r) * C_ + gc] = acc[m][n][r] * inv[r];
        }
    }
#undef STAGE1
#undef COMPUTE_T
#undef EXPAND
}

// ---------------------------------------------------------------------------
extern "C" void kernel_launch(void* const* d_in, const int* in_sizes, int n_in,
                              void* d_out, int out_size, void* d_ws, size_t ws_size,
                              hipStream_t stream) {
    const float* x        = (const float*)d_in[0];
    const int*   adj      = (const int*)d_in[1];
    const float* weight   = (const float*)d_in[2];
    // d_in[3] = attn_src : unused (cancels in softmax over neighbors j)
    const float* attn_dst = (const float*)d_in[4];
    float* out = (float*)d_out;

    // workspace:
    //   xb  : 4 MiB bf16
    //   wbT : 256 KiB bf16
    //   ebT : 128 KiB bf16   [b][h][j]
    //   gT  : 8 MiB bf16     [b][c][j]
    //   bm  : 2 MiB bitmask  [b*N + i][N/8 bytes]
    short* xb  = (short*)d_ws;
    short* wbT = xb + (size_t)B_ * N_ * INF_;
    short* ebT = wbT + (size_t)C_ * INF_;
    short* gT  = ebT + (size_t)B_ * H_ * N_;
    unsigned char* bmp = (unsigned char*)(gT + (size_t)B_ * C_ * N_);

    // 1. small casts: x->xb, W->wbT
    cast_xw<<<dim3(1024 + 32), 256, 0, stream>>>(x, weight, xb, wbT);
    // 2. merged projection(+e+gT) and adj->bitmask pack (overlapping pipes)
    proj_pack<<<dim3(1024), 256, 0, stream>>>(xb, wbT, attn_dst, adj, ebT, gT, bmp);
    // 3. numerator GEMM + denominator (MFMA pipeline) + divide -> out
    agg_mfma<<<dim3(512), 512, 0, stream>>>(bmp, gT, ebT, out);
}